// Round 13
// baseline (571.156 us; speedup 1.0000x reference)
//
#include <hip/hip_runtime.h>
#include <math.h>

// Dims: N=128, C=128, T=64, V=25, S=3, R=32; TV=1600, CTV=204800.
// qk [n][192r][1600tv] bf16 lives in d_out (dead until final write).
// y_bf [n][1600tv][128c] bf16 in ws[0,52.4M) — the ONLY materialization of y.
// attS_bf: [n][32v][96k] (k=s*32+u). attT_bf: [n][64q][192k] (k=s*64+t).
// s_fused: x+attS -> y_bf (t1+s2+cbr in LDS). t_fused: y_bf+attT -> final out (t1+t2+cbr in LDS).

typedef __attribute__((ext_vector_type(8))) short short8v;
typedef __attribute__((ext_vector_type(4))) float f32x4;

__device__ __forceinline__ ushort f2bf(float f) {
    uint b = __float_as_uint(f);
    uint r = b + 0x7fffu + ((b >> 16) & 1u);
    return (ushort)(r >> 16);
}
__device__ __forceinline__ float bf2f(ushort h) {
    return __uint_as_float(((uint)h) << 16);
}

// -------- weight prep (bf16 copies) --------
__global__ __launch_bounds__(256) void wt_prep(
    const float* __restrict__ Wo_s, const float* __restrict__ Wf_s,
    const float* __restrict__ Wo_t, const float* __restrict__ Wf_t,
    const float* __restrict__ Wqk_s, const float* __restrict__ Wqk_t,
    ushort* __restrict__ W16)
{
    int idx = blockIdx.x * 256 + threadIdx.x;
    if (idx >= 180224) return;
    float v;
    if (idx < 49152) {
        int s = idx / 16384, rem = idx % 16384, o = rem / 128, c = rem % 128;
        v = Wo_s[o * 384 + s * 128 + c];
    } else if (idx < 65536) {
        v = Wf_s[idx - 49152];
    } else if (idx < 114688) {
        int i = idx - 65536, s = i / 16384, rem = i % 16384, o = rem / 128, c = rem % 128;
        v = Wo_t[o * 384 + s * 128 + c];
    } else if (idx < 131072) {
        v = Wf_t[idx - 114688];
    } else if (idx < 155648) {
        v = Wqk_s[idx - 131072];
    } else {
        v = Wqk_t[idx - 155648];
    }
    W16[idx] = f2bf(v);
}

// -------- qk_pe (MFMA, fp32 src + spatial PE): qk[n][192r][1600tv] --------
__global__ __launch_bounds__(256) void qk_pe_mfma(
    const float* __restrict__ src, const ushort* __restrict__ Wbf,
    const float* __restrict__ bias, ushort* __restrict__ out)
{
    __shared__ __align__(16) ushort xT[160 * 136];
    __shared__ __align__(16) ushort exch[192 * 24];
    const int n = blockIdx.y, tvb = blockIdx.x * 160;
    const float* sn = src + (size_t)n * 204800;
    for (int i = threadIdx.x; i < 2560; i += 256) {
        int tv4 = (i & 7) + (i >> 9) * 8;
        int cp  = (i >> 3) & 63;
        float4 a = *(const float4*)(sn + (2 * cp) * 1600 + tvb + tv4 * 4);
        float4 b = *(const float4*)(sn + (2 * cp + 1) * 1600 + tvb + tv4 * 4);
        float dv = __expf(-0.14391156831212787f * (float)cp);
        float av[4] = { a.x, a.y, a.z, a.w };
        float bv[4] = { b.x, b.y, b.z, b.w };
#pragma unroll
        for (int e = 0; e < 4; e++) {
            int tv = tvb + tv4 * 4 + e;
            int tt = tv / 25;
            float pos = (float)(tv - tt * 25);   // spatial PE
            float ang = pos * dv;
            uint p = (uint)f2bf(av[e] + __sinf(ang)) | ((uint)f2bf(bv[e] + __cosf(ang)) << 16);
            ((uint*)xT)[(tv4 * 4 + e) * 68 + cp] = p;
        }
    }
    __syncthreads();
    const int lane = threadIdx.x & 63, wave = threadIdx.x >> 6;
    const int l15 = lane & 15, kg = lane >> 4;
    const int rb = wave * 48;
    short8v wf[3][4];
#pragma unroll
    for (int nt = 0; nt < 3; nt++)
#pragma unroll
        for (int k = 0; k < 4; k++)
            wf[nt][k] = *(const short8v*)&Wbf[(rb + nt * 16 + l15) * 128 + k * 32 + kg * 8];
    float bsv[3];
#pragma unroll
    for (int nt = 0; nt < 3; nt++) bsv[nt] = bias[rb + nt * 16 + l15];
    ushort* on = out + (size_t)n * 307200;
    for (int mt = 0; mt < 10; mt++) {
        short8v af[4];
#pragma unroll
        for (int k = 0; k < 4; k++)
            af[k] = *(short8v*)&xT[(mt * 16 + l15) * 136 + k * 32 + kg * 8];
        f32x4 accs[3];
#pragma unroll
        for (int nt = 0; nt < 3; nt++) {
            f32x4 acc = {0.f, 0.f, 0.f, 0.f};
#pragma unroll
            for (int k = 0; k < 4; k++)
                acc = __builtin_amdgcn_mfma_f32_16x16x32_bf16(af[k], wf[nt][k], acc, 0, 0, 0);
            accs[nt] = acc;
        }
        __syncthreads();
#pragma unroll
        for (int nt = 0; nt < 3; nt++) {
            uint2 pk;
            pk.x = (uint)f2bf(accs[nt][0] + bsv[nt]) | ((uint)f2bf(accs[nt][1] + bsv[nt]) << 16);
            pk.y = (uint)f2bf(accs[nt][2] + bsv[nt]) | ((uint)f2bf(accs[nt][3] + bsv[nt]) << 16);
            *(uint2*)&exch[(rb + nt * 16 + l15) * 24 + kg * 4] = pk;
        }
        __syncthreads();
        for (int i = threadIdx.x; i < 384; i += 256) {
            int r = i >> 1, hh = i & 1;
            *(uint4*)(on + (size_t)r * 1600 + tvb + mt * 16 + hh * 8) =
                *(const uint4*)&exch[r * 24 + hh * 8];
        }
    }
}

// -------- qk_pe_bf (MFMA, bf16 y src + temporal PE): qk[n][192r][1600tv] --------
__global__ __launch_bounds__(256) void qk_pe_bf(
    const ushort* __restrict__ ybf, const ushort* __restrict__ Wbf,
    const float* __restrict__ bias, ushort* __restrict__ out)
{
    __shared__ __align__(16) ushort xT[160 * 136];
    __shared__ __align__(16) ushort exch[192 * 24];
    const int n = blockIdx.y, tvb = blockIdx.x * 160;
    const ushort* yq = ybf + (size_t)n * 204800;
    for (int i = threadIdx.x; i < 10240; i += 256) {
        int tv = i >> 6, cp = i & 63;
        uint w = *(const uint*)(yq + (size_t)(tvb + tv) * 128 + cp * 2);
        int t = (tvb + tv) / 25;
        float dv = __expf(-0.14391156831212787f * (float)cp);
        float ang = (float)t * dv;
        float lo = bf2f((ushort)(w & 0xffffu)) + __sinf(ang);
        float hi = bf2f((ushort)(w >> 16)) + __cosf(ang);
        ((uint*)xT)[tv * 68 + cp] = (uint)f2bf(lo) | ((uint)f2bf(hi) << 16);
    }
    __syncthreads();
    const int lane = threadIdx.x & 63, wave = threadIdx.x >> 6;
    const int l15 = lane & 15, kg = lane >> 4;
    const int rb = wave * 48;
    short8v wf[3][4];
#pragma unroll
    for (int nt = 0; nt < 3; nt++)
#pragma unroll
        for (int k = 0; k < 4; k++)
            wf[nt][k] = *(const short8v*)&Wbf[(rb + nt * 16 + l15) * 128 + k * 32 + kg * 8];
    float bsv[3];
#pragma unroll
    for (int nt = 0; nt < 3; nt++) bsv[nt] = bias[rb + nt * 16 + l15];
    ushort* on = out + (size_t)n * 307200;
    for (int mt = 0; mt < 10; mt++) {
        short8v af[4];
#pragma unroll
        for (int k = 0; k < 4; k++)
            af[k] = *(short8v*)&xT[(mt * 16 + l15) * 136 + k * 32 + kg * 8];
        f32x4 accs[3];
#pragma unroll
        for (int nt = 0; nt < 3; nt++) {
            f32x4 acc = {0.f, 0.f, 0.f, 0.f};
#pragma unroll
            for (int k = 0; k < 4; k++)
                acc = __builtin_amdgcn_mfma_f32_16x16x32_bf16(af[k], wf[nt][k], acc, 0, 0, 0);
            accs[nt] = acc;
        }
        __syncthreads();
#pragma unroll
        for (int nt = 0; nt < 3; nt++) {
            uint2 pk;
            pk.x = (uint)f2bf(accs[nt][0] + bsv[nt]) | ((uint)f2bf(accs[nt][1] + bsv[nt]) << 16);
            pk.y = (uint)f2bf(accs[nt][2] + bsv[nt]) | ((uint)f2bf(accs[nt][3] + bsv[nt]) << 16);
            *(uint2*)&exch[(rb + nt * 16 + l15) * 24 + kg * 4] = pk;
        }
        __syncthreads();
        for (int i = threadIdx.x; i < 384; i += 256) {
            int r = i >> 1, hh = i & 1;
            *(uint4*)(on + (size_t)r * 1600 + tvb + mt * 16 + hh * 8) =
                *(const uint4*)&exch[r * 24 + hh * 8];
        }
    }
}

// -------- att_s (MFMA) -> attS_bf[n][32v][96k] bf16, k=s*32+u, pads zeroed --------
__global__ __launch_bounds__(256) void att_s_mfma(
    const ushort* __restrict__ qk, const float* __restrict__ alphas,
    const float* __restrict__ att0, ushort* __restrict__ attS_bf)
{
    __shared__ __align__(16) ushort Qs[32 * 520];
    __shared__ __align__(16) ushort Ks[32 * 520];
    const int s = blockIdx.x, n = blockIdx.y;
    const ushort* qb = qk + (size_t)n * 307200 + (size_t)(s * 32) * 1600;
    const ushort* kb = qb + 96 * 1600;
    for (int i = threadIdx.x; i < 3072; i += 256) {
        int v = i / 96, k = i - v * 96;
        if (v >= 25 || (k & 31) >= 25) attS_bf[(size_t)n * 3072 + i] = 0;
    }
    const int lane = threadIdx.x & 63, wave = threadIdx.x >> 6;
    const int l15 = lane & 15, kg = lane >> 4;
    const int mt = wave >> 1, nt = wave & 1;
    f32x4 acc = {0.f, 0.f, 0.f, 0.f};
    for (int rc = 0; rc < 4; rc++) {
        __syncthreads();
        for (int i = threadIdx.x; i < 6400; i += 256) {
            int rl = i / 800, j = i - rl * 800;
            uint uq = *(const uint*)(qb + (rc * 8 + rl) * 1600 + j * 2);
            uint uk = *(const uint*)(kb + (rc * 8 + rl) * 1600 + j * 2);
            int tv = j * 2;
            int t0 = tv / 25, u0 = tv - t0 * 25;
            int t1 = (tv + 1) / 25, u1 = (tv + 1) - t1 * 25;
            Qs[u0 * 520 + rl * 64 + t0] = (ushort)(uq & 0xffffu);
            Qs[u1 * 520 + rl * 64 + t1] = (ushort)(uq >> 16);
            Ks[u0 * 520 + rl * 64 + t0] = (ushort)(uk & 0xffffu);
            Ks[u1 * 520 + rl * 64 + t1] = (ushort)(uk >> 16);
        }
        __syncthreads();
#pragma unroll
        for (int ks = 0; ks < 16; ks++) {
            short8v a = *(const short8v*)&Qs[(mt * 16 + l15) * 520 + ks * 32 + kg * 8];
            short8v b = *(const short8v*)&Ks[(nt * 16 + l15) * 520 + ks * 32 + kg * 8];
            acc = __builtin_amdgcn_mfma_f32_16x16x32_bf16(a, b, acc, 0, 0, 0);
        }
    }
    float alpha = alphas[s];
#pragma unroll
    for (int rr = 0; rr < 4; rr++) {
        int u = mt * 16 + kg * 4 + rr, v = nt * 16 + l15;
        if (u < 25 && v < 25)
            attS_bf[(size_t)n * 3072 + v * 96 + s * 32 + u] =
                f2bf(tanhf(acc[rr] * (1.0f / 2048.0f)) * alpha + att0[s * 625 + u * 25 + v]);
    }
}

// -------- att_t (MFMA) -> attT_bf[n][64q][192k] bf16, k=s*64+t --------
__global__ __launch_bounds__(256) void att_t_mfma(
    const ushort* __restrict__ qk, const float* __restrict__ alphat,
    const float* __restrict__ att0, ushort* __restrict__ attT_bf)
{
    __shared__ __align__(16) ushort Qt[8 * 64 * 40];
    __shared__ __align__(16) ushort Kt[8 * 64 * 40];
    const int s = blockIdx.x, n = blockIdx.y;
    const ushort* qb = qk + (size_t)n * 307200 + (size_t)(s * 32) * 1600;
    const ushort* kb = qb + 96 * 1600;
    for (int i = threadIdx.x; i < 10240; i += 256) {
        ((uint*)Qt)[i] = 0u;
        ((uint*)Kt)[i] = 0u;
    }
    const int lane = threadIdx.x & 63, wave = threadIdx.x >> 6;
    const int l15 = lane & 15, kg = lane >> 4;
    const int mt = wave;
    f32x4 acc[4];
#pragma unroll
    for (int i = 0; i < 4; i++) acc[i] = (f32x4){0.f, 0.f, 0.f, 0.f};
    for (int rc = 0; rc < 4; rc++) {
        __syncthreads();
        for (int i = threadIdx.x; i < 6400; i += 256) {
            int rl = i / 800, j = i - rl * 800;
            uint uq = *(const uint*)(qb + (rc * 8 + rl) * 1600 + j * 2);
            uint uk = *(const uint*)(kb + (rc * 8 + rl) * 1600 + j * 2);
            int tv = j * 2;
            int t0 = tv / 25, v0 = tv - t0 * 25;
            int t1 = (tv + 1) / 25, v1 = (tv + 1) - t1 * 25;
            Qt[(rl * 64 + t0) * 40 + v0] = (ushort)(uq & 0xffffu);
            Qt[(rl * 64 + t1) * 40 + v1] = (ushort)(uq >> 16);
            Kt[(rl * 64 + t0) * 40 + v0] = (ushort)(uk & 0xffffu);
            Kt[(rl * 64 + t1) * 40 + v1] = (ushort)(uk >> 16);
        }
        __syncthreads();
#pragma unroll
        for (int rl = 0; rl < 8; rl++) {
            short8v a = *(const short8v*)&Qt[(rl * 64 + mt * 16 + l15) * 40 + kg * 8];
#pragma unroll
            for (int nq = 0; nq < 4; nq++) {
                short8v b = *(const short8v*)&Kt[(rl * 64 + nq * 16 + l15) * 40 + kg * 8];
                acc[nq] = __builtin_amdgcn_mfma_f32_16x16x32_bf16(a, b, acc[nq], 0, 0, 0);
            }
        }
    }
    float alpha = alphat[s];
#pragma unroll
    for (int nq = 0; nq < 4; nq++) {
        int q = nq * 16 + l15;
        ushort w4[4];
#pragma unroll
        for (int rr = 0; rr < 4; rr++) {
            int t = mt * 16 + kg * 4 + rr;
            w4[rr] = f2bf(tanhf(acc[nq][rr] * (1.0f / 800.0f)) * alpha +
                          att0[s * 4096 + t * 64 + q]);
        }
        uint2 pk;
        pk.x = (uint)w4[0] | ((uint)w4[1] << 16);
        pk.y = (uint)w4[2] | ((uint)w4[3] << 16);
        *(uint2*)(attT_bf + (size_t)n * 12288 + q * 192 + s * 64 + mt * 16 + kg * 4) = pk;
    }
}

// ------- s_fused: spatial post-attention, one block per (n, 2t); emits y_bf[tv][128c] -------
__global__ __launch_bounds__(256) void s_fused(
    const float* __restrict__ x, const ushort* __restrict__ Wo /*[3][128o][128c]*/,
    const ushort* __restrict__ attS /*[n][32v][96k]*/, const ushort* __restrict__ Wf,
    const float* __restrict__ bnO, const float* __restrict__ boO,
    const float* __restrict__ bnF, const float* __restrict__ bfF,
    ushort* __restrict__ ybf)
{
    __shared__ __align__(16) ushort xT[64 * 136];   // [tv_local][c] (rows 50..63 unused)
    __shared__ __align__(16) ushort uni[64 * 136];  // phase1: Bt[256*32]; phase2: y1[tv][c]; phase3: out exch
    __shared__ float sc1[128], of1[128], sc2[128], of2[128];
    const int n = blockIdx.y, tb = blockIdx.x;
    const int tvg0 = tb * 50;
    if (threadIdx.x < 128) {
        int o = threadIdx.x;
        float s1 = bnO[o] * rsqrtf(bnO[384 + o] + 1e-5f);
        sc1[o] = s1; of1[o] = (boO[o] - bnO[256 + o]) * s1 + bnO[128 + o];
    } else {
        int o = threadIdx.x - 128;
        float s2 = bnF[o] * rsqrtf(bnF[384 + o] + 1e-5f);
        sc2[o] = s2; of2[o] = (bfF[o] - bnF[256 + o]) * s2 + bnF[128 + o];
    }
    ushort* Bt = uni;
    for (int i = threadIdx.x; i < 1792; i += 256) {
        int nr = i / 7, k = 25 + i % 7;
        Bt[nr * 32 + (((k >> 3) ^ ((nr >> 1) & 3)) << 3) + (k & 7)] = 0;
    }
    const float* xn = x + (size_t)n * 204800;
    for (int i = threadIdx.x; i < 3200; i += 256) {
        int c = i / 25, j2 = i - c * 25;
        float2 v2 = *(const float2*)(xn + c * 1600 + tvg0 + j2 * 2);
        xT[(j2 * 2) * 136 + c]     = f2bf(v2.x);
        xT[(j2 * 2 + 1) * 136 + c] = f2bf(v2.y);
    }
    __syncthreads();
    const int lane = threadIdx.x & 63, wave = threadIdx.x >> 6;
    const int l15 = lane & 15, kg = lane >> 4;
    const int ob = wave * 32, jb = wave * 4;
    f32x4 accS[2][4];
#pragma unroll
    for (int mt = 0; mt < 2; mt++)
#pragma unroll
        for (int jj = 0; jj < 4; jj++) accS[mt][jj] = (f32x4){0.f, 0.f, 0.f, 0.f};
    const ushort* An = attS + (size_t)n * 3072;
    for (int s = 0; s < 3; s++) {
        short8v bW[2][4];
#pragma unroll
        for (int ot = 0; ot < 2; ot++)
#pragma unroll
            for (int k = 0; k < 4; k++)
                bW[ot][k] = *(const short8v*)&Wo[s * 16384 +
                             (ob + ot * 16 + l15) * 128 + k * 32 + kg * 8];
#pragma unroll
        for (int tt = 0; tt < 4; tt++) {
            short8v aX[4];
#pragma unroll
            for (int k = 0; k < 4; k++)
                aX[k] = *(short8v*)&xT[(tt * 16 + l15) * 136 + k * 32 + kg * 8];
            f32x4 h0 = {0.f, 0.f, 0.f, 0.f}, h1 = {0.f, 0.f, 0.f, 0.f};
#pragma unroll
            for (int k = 0; k < 4; k++) {
                h0 = __builtin_amdgcn_mfma_f32_16x16x32_bf16(aX[k], bW[0][k], h0, 0, 0, 0);
                h1 = __builtin_amdgcn_mfma_f32_16x16x32_bf16(aX[k], bW[1][k], h1, 0, 0, 0);
            }
#pragma unroll
            for (int rr = 0; rr < 4; rr++) {
                int tv = tt * 16 + kg * 4 + rr;
                if (tv < 50) {
                    int tl = tv >= 25 ? 1 : 0, u = tv - tl * 25;
                    int n0 = tl * 128 + ob + l15;
                    int n1 = n0 + 16;
                    Bt[n0 * 32 + (((u >> 3) ^ ((n0 >> 1) & 3)) << 3) + (u & 7)] = f2bf(h0[rr]);
                    Bt[n1 * 32 + (((u >> 3) ^ ((n1 >> 1) & 3)) << 3) + (u & 7)] = f2bf(h1[rr]);
                }
            }
        }
        __syncthreads();
        short8v aA[2];
#pragma unroll
        for (int mt = 0; mt < 2; mt++)
            aA[mt] = *(const short8v*)(An + (mt * 16 + l15) * 96 + s * 32 + kg * 8);
#pragma unroll
        for (int jj = 0; jj < 4; jj++) {
            int nr = (jb + jj) * 16 + l15;
            short8v b = *(const short8v*)&Bt[nr * 32 + ((kg ^ ((nr >> 1) & 3)) << 3)];
#pragma unroll
            for (int mt = 0; mt < 2; mt++)
                accS[mt][jj] = __builtin_amdgcn_mfma_f32_16x16x32_bf16(aA[mt], b, accS[mt][jj], 0, 0, 0);
        }
        __syncthreads();
    }
    // phase 2: y1 = lrelu(x + BN1(accS)) -> uni[tv][c]  (Bt dead)
#pragma unroll
    for (int mt = 0; mt < 2; mt++)
#pragma unroll
        for (int jj = 0; jj < 4; jj++) {
            int nr = (jb + jj) * 16 + l15;
            int tl = nr >> 7, o = nr & 127;
            float sc = sc1[o], of = of1[o];
#pragma unroll
            for (int rr = 0; rr < 4; rr++) {
                int v = mt * 16 + kg * 4 + rr;
                if (v < 25) {
                    int tvl = tl * 25 + v;
                    float h = accS[mt][jj][rr] * sc + of + bf2f(xT[tvl * 136 + o]);
                    h = h > 0.f ? h : 0.1f * h;
                    uni[tvl * 136 + o] = f2bf(h);
                }
            }
        }
    __syncthreads();
    // phase 3: out = lrelu(x + BN2(Wf @ y1)), accumulate in regs
    short8v aF[2][4];
#pragma unroll
    for (int mt = 0; mt < 2; mt++)
#pragma unroll
        for (int k = 0; k < 4; k++)
            aF[mt][k] = *(const short8v*)&Wf[(ob + mt * 16 + l15) * 128 + k * 32 + kg * 8];
    f32x4 c0s[4], c1s[4];
#pragma unroll
    for (int nt = 0; nt < 4; nt++) {
        short8v bY[4];
#pragma unroll
        for (int k = 0; k < 4; k++)
            bY[k] = *(short8v*)&uni[(nt * 16 + l15) * 136 + k * 32 + kg * 8];
        f32x4 c0 = {0.f, 0.f, 0.f, 0.f}, c1 = {0.f, 0.f, 0.f, 0.f};
#pragma unroll
        for (int k = 0; k < 4; k++) {
            c0 = __builtin_amdgcn_mfma_f32_16x16x32_bf16(aF[0][k], bY[k], c0, 0, 0, 0);
            c1 = __builtin_amdgcn_mfma_f32_16x16x32_bf16(aF[1][k], bY[k], c1, 0, 0, 0);
        }
        c0s[nt] = c0; c1s[nt] = c1;
    }
    __syncthreads();
    // exchange out values through uni as [tv][c]
#pragma unroll
    for (int nt = 0; nt < 4; nt++) {
        int tv = nt * 16 + l15;
#pragma unroll
        for (int rr = 0; rr < 4; rr++) {
            {
                int o = ob + kg * 4 + rr;
                float h = c0s[nt][rr] * sc2[o] + of2[o] + bf2f(xT[tv * 136 + o]);
                uni[tv * 136 + o] = f2bf(h > 0.f ? h : 0.1f * h);
            }
            {
                int o = ob + 16 + kg * 4 + rr;
                float h = c1s[nt][rr] * sc2[o] + of2[o] + bf2f(xT[tv * 136 + o]);
                uni[tv * 136 + o] = f2bf(h > 0.f ? h : 0.1f * h);
            }
        }
    }
    __syncthreads();
    // drain rows tv<50 linearly to y_bf
    uint* dst = (uint*)(ybf + (size_t)n * 204800 + (size_t)tvg0 * 128);
    for (int i = threadIdx.x; i < 3200; i += 256) {
        int tv = i >> 6, cp = i & 63;
        dst[tv * 64 + cp] = ((const uint*)uni)[tv * 68 + cp];
    }
}

// ------- t_fused: temporal t1+t2+res+Wf-conv+res per (n, v); writes final fp32 out -------
__global__ __launch_bounds__(256) void t_fused(
    const ushort* __restrict__ ybf, const ushort* __restrict__ Wo /*[3][128o][128c]*/,
    const ushort* __restrict__ Wf /*[128o][128c]*/,
    const ushort* __restrict__ attT /*[n][64q][192]*/,
    const float* __restrict__ bn1, const float* __restrict__ bo1,
    const float* __restrict__ bn2, const float* __restrict__ bf2v,
    float* __restrict__ outp)
{
    __shared__ __align__(16) ushort yS[64 * 136];   // [t][c] residual + t1 input (live whole kernel)
    __shared__ __align__(16) ushort uni[128 * 72];  // phase1: Gl[o][72]; phase2: y1[q][136] (8704<=9216)
    __shared__ float sc1[128], of1[128], sc2[128], of2[128];
    const int v = blockIdx.x, np = blockIdx.y;
    if (threadIdx.x < 128) {
        int o = threadIdx.x;
        float sc = bn1[o] * rsqrtf(bn1[384 + o] + 1e-5f);
        sc1[o] = sc;
        of1[o] = (bo1[o] - bn1[256 + o]) * sc + bn1[128 + o];
    } else {
        int o = threadIdx.x - 128;
        float sc = bn2[o] * rsqrtf(bn2[384 + o] + 1e-5f);
        sc2[o] = sc;
        of2[o] = (bf2v[o] - bn2[256 + o]) * sc + bn2[128 + o];
    }
    const ushort* yq = ybf + (size_t)np * 204800;
    for (int i = threadIdx.x; i < 4096; i += 256) {
        int t = i >> 6, cp = i & 63;
        ((uint*)yS)[t * 68 + cp] = *(const uint*)(yq + (size_t)(t * 25 + v) * 128 + cp * 2);
    }
    __syncthreads();
    const int lane = threadIdx.x & 63, wave = threadIdx.x >> 6;
    const int l15 = lane & 15, kg = lane >> 4;
    const int ob = wave * 32;
    const ushort* An = attT + (size_t)np * 12288;
    ushort* Gl = uni;
    f32x4 acc[4][2];
#pragma unroll
    for (int mt = 0; mt < 4; mt++)
#pragma unroll
        for (int jj = 0; jj < 2; jj++) acc[mt][jj] = (f32x4){0.f, 0.f, 0.f, 0.f};
    for (int s = 0; s < 3; s++) {
        short8v bW[2][4];
#pragma unroll
        for (int nt = 0; nt < 2; nt++)
#pragma unroll
            for (int k = 0; k < 4; k++)
                bW[nt][k] = *(const short8v*)&Wo[s * 16384 +
                             (ob + nt * 16 + l15) * 128 + k * 32 + kg * 8];
#pragma unroll
        for (int mt = 0; mt < 4; mt++) {
            short8v aX[4];
#pragma unroll
            for (int k = 0; k < 4; k++)
                aX[k] = *(short8v*)&yS[(mt * 16 + l15) * 136 + k * 32 + kg * 8];
            f32x4 g0 = {0.f, 0.f, 0.f, 0.f}, g1 = {0.f, 0.f, 0.f, 0.f};
#pragma unroll
            for (int k = 0; k < 4; k++) {
                g0 = __builtin_amdgcn_mfma_f32_16x16x32_bf16(aX[k], bW[0][k], g0, 0, 0, 0);
                g1 = __builtin_amdgcn_mfma_f32_16x16x32_bf16(aX[k], bW[1][k], g1, 0, 0, 0);
            }
#pragma unroll
            for (int rr = 0; rr < 4; rr++) {
                int t = mt * 16 + kg * 4 + rr;
                Gl[(ob + l15) * 72 + t]      = f2bf(g0[rr]);
                Gl[(ob + 16 + l15) * 72 + t] = f2bf(g1[rr]);
            }
        }
        __syncthreads();
#pragma unroll
        for (int ks = 0; ks < 2; ks++) {
            short8v b2[2];
#pragma unroll
            for (int jj = 0; jj < 2; jj++)
                b2[jj] = *(short8v*)&Gl[(ob + jj * 16 + l15) * 72 + ks * 32 + kg * 8];
#pragma unroll
            for (int mt = 0; mt < 4; mt++) {
                short8v a2 = *(const short8v*)(An + (mt * 16 + l15) * 192 + s * 64 + ks * 32 + kg * 8);
#pragma unroll
                for (int jj = 0; jj < 2; jj++)
                    acc[mt][jj] = __builtin_amdgcn_mfma_f32_16x16x32_bf16(a2, b2[jj], acc[mt][jj], 0, 0, 0);
            }
        }
        __syncthreads();
    }
    // phase 2: y1[q][c] = lrelu(y + BN1(acc)) into uni (Gl dead)
#pragma unroll
    for (int mt = 0; mt < 4; mt++)
#pragma unroll
        for (int jj = 0; jj < 2; jj++) {
            int o = ob + jj * 16 + l15;
            float sc = sc1[o], of = of1[o];
#pragma unroll
            for (int rr = 0; rr < 4; rr++) {
                int q = mt * 16 + kg * 4 + rr;
                float h = acc[mt][jj][rr] * sc + of + bf2f(yS[q * 136 + o]);
                h = h > 0.f ? h : 0.1f * h;
                uni[q * 136 + o] = f2bf(h);
            }
        }
    __syncthreads();
    // phase 3: out[o][q*25+v] = lrelu(y + BN2(Wf @ y1))
    short8v aF[2][4];
#pragma unroll
    for (int ot = 0; ot < 2; ot++)
#pragma unroll
        for (int k = 0; k < 4; k++)
            aF[ot][k] = *(const short8v*)&Wf[(ob + ot * 16 + l15) * 128 + k * 32 + kg * 8];
    float* out_n = outp + (size_t)np * 204800;
#pragma unroll
    for (int qt = 0; qt < 4; qt++) {
        short8v bY[4];
#pragma unroll
        for (int k = 0; k < 4; k++)
            bY[k] = *(short8v*)&uni[(qt * 16 + l15) * 136 + k * 32 + kg * 8];
        f32x4 c0 = {0.f, 0.f, 0.f, 0.f}, c1 = {0.f, 0.f, 0.f, 0.f};
#pragma unroll
        for (int k = 0; k < 4; k++) {
            c0 = __builtin_amdgcn_mfma_f32_16x16x32_bf16(aF[0][k], bY[k], c0, 0, 0, 0);
            c1 = __builtin_amdgcn_mfma_f32_16x16x32_bf16(aF[1][k], bY[k], c1, 0, 0, 0);
        }
        int q = qt * 16 + l15;
#pragma unroll
        for (int rr = 0; rr < 4; rr++) {
            {
                int o = ob + kg * 4 + rr;
                float h = c0[rr] * sc2[o] + of2[o] + bf2f(yS[q * 136 + o]);
                out_n[(size_t)o * 1600 + q * 25 + v] = h > 0.f ? h : 0.1f * h;
            }
            {
                int o = ob + 16 + kg * 4 + rr;
                float h = c1[rr] * sc2[o] + of2[o] + bf2f(yS[q * 136 + o]);
                out_n[(size_t)o * 1600 + q * 25 + v] = h > 0.f ? h : 0.1f * h;
            }
        }
    }
}

extern "C" void kernel_launch(void* const* d_in, const int* in_sizes, int n_in,
                              void* d_out, int out_size, void* d_ws, size_t ws_size,
                              hipStream_t stream)
{
    (void)in_sizes; (void)n_in; (void)out_size; (void)ws_size;
    const float* x      = (const float*)d_in[0];
    const float* Wqk_s  = (const float*)d_in[1];
    const float* bqk_s  = (const float*)d_in[2];
    const float* alphas = (const float*)d_in[3];
    const float* att0s  = (const float*)d_in[4];
    const float* Wo_s   = (const float*)d_in[5];
    const float* bo_s   = (const float*)d_in[6];
    const float* bn_o_s = (const float*)d_in[7];
    const float* Wf_s   = (const float*)d_in[8];
    const float* bf_s   = (const float*)d_in[9];
    const float* bn_f_s = (const float*)d_in[10];
    const float* Wqk_t  = (const float*)d_in[11];
    const float* bqk_t  = (const float*)d_in[12];
    const float* alphat = (const float*)d_in[13];
    const float* att0t  = (const float*)d_in[14];
    const float* Wo_t   = (const float*)d_in[15];
    const float* bo_t   = (const float*)d_in[16];
    const float* bn_o_t = (const float*)d_in[17];
    const float* Wf_t   = (const float*)d_in[18];
    const float* bf_t   = (const float*)d_in[19];
    const float* bn_f_t = (const float*)d_in[20];

    float* out = (float*)d_out;
    // qk (78.6 MB bf16) lives in d_out — dead by the time t_fused writes the real output.
    ushort* qk_d    = (ushort*)d_out;
    // ws: y_bf [0, 52.4M); attS at 78.6M; attT at 79.6M; W16 at 85.9M (all proven offsets).
    ushort* ybf     = (ushort*)d_ws;
    ushort* attS_bf = (ushort*)((char*)d_ws + 78643200);
    ushort* attT_bf = (ushort*)((char*)d_ws + 79603200);
    ushort* W16     = (ushort*)((char*)d_ws + 85894656);
    const ushort* WoS_bf  = W16;
    const ushort* WfS_bf  = W16 + 49152;
    const ushort* WoT_bf  = W16 + 65536;
    const ushort* WfT_bf  = W16 + 114688;
    const ushort* WqkS_bf = W16 + 131072;
    const ushort* WqkT_bf = W16 + 155648;

    wt_prep<<<704, 256, 0, stream>>>(Wo_s, Wf_s, Wo_t, Wf_t, Wqk_s, Wqk_t, W16);

    dim3 gqk(10, 128), gatt(3, 128), gsf(32, 128), gtf(25, 128);

    // ---- spatial ----
    qk_pe_mfma<<<gqk, 256, 0, stream>>>(x, WqkS_bf, bqk_s, qk_d);
    att_s_mfma<<<gatt, 256, 0, stream>>>(qk_d, alphas, att0s, attS_bf);
    s_fused<<<gsf, 256, 0, stream>>>(x, WoS_bf, attS_bf, WfS_bf,
                                     bn_o_s, bo_s, bn_f_s, bf_s, ybf);

    // ---- temporal ----
    qk_pe_bf<<<gqk, 256, 0, stream>>>(ybf, WqkT_bf, bqk_t, qk_d);
    att_t_mfma<<<gatt, 256, 0, stream>>>(qk_d, alphat, att0t, attT_bf);
    t_fused<<<gtf, 256, 0, stream>>>(ybf, WoT_bf, WfT_bf, attT_bf,
                                     bn_o_t, bo_t, bn_f_t, bf_t, out);
}

// Round 14
// 417.944 us; speedup vs baseline: 1.3666x; 1.3666x over previous
//
#include <hip/hip_runtime.h>
#include <math.h>

// Dims: N=128, C=128, T=64, V=25, S=3, R=32; TV=1600, CTV=204800.
// qk [n][192r][1600tv] bf16 lives in d_out (dead until z_out writes final output).
// y_bf [n][1600tv][128c] bf16 in ws[0,52.4M); t_fused overwrites it in place with z (same rows).
// attS_bf: [n][32v][96k] (k=s*32+u). attT_bf: [n][64q][192k] (k=s*64+t).

typedef __attribute__((ext_vector_type(8))) short short8v;
typedef __attribute__((ext_vector_type(4))) float f32x4;

__device__ __forceinline__ ushort f2bf(float f) {
    uint b = __float_as_uint(f);
    uint r = b + 0x7fffu + ((b >> 16) & 1u);
    return (ushort)(r >> 16);
}
__device__ __forceinline__ float bf2f(ushort h) {
    return __uint_as_float(((uint)h) << 16);
}

// -------- weight prep (bf16 copies) --------
__global__ __launch_bounds__(256) void wt_prep(
    const float* __restrict__ Wo_s, const float* __restrict__ Wf_s,
    const float* __restrict__ Wo_t, const float* __restrict__ Wf_t,
    const float* __restrict__ Wqk_s, const float* __restrict__ Wqk_t,
    ushort* __restrict__ W16)
{
    int idx = blockIdx.x * 256 + threadIdx.x;
    if (idx >= 180224) return;
    float v;
    if (idx < 49152) {
        int s = idx / 16384, rem = idx % 16384, o = rem / 128, c = rem % 128;
        v = Wo_s[o * 384 + s * 128 + c];
    } else if (idx < 65536) {
        v = Wf_s[idx - 49152];
    } else if (idx < 114688) {
        int i = idx - 65536, s = i / 16384, rem = i % 16384, o = rem / 128, c = rem % 128;
        v = Wo_t[o * 384 + s * 128 + c];
    } else if (idx < 131072) {
        v = Wf_t[idx - 114688];
    } else if (idx < 155648) {
        v = Wqk_s[idx - 131072];
    } else {
        v = Wqk_t[idx - 155648];
    }
    W16[idx] = f2bf(v);
}

// -------- qk_pe (MFMA, fp32 src + spatial PE): qk[n][192r][1600tv] --------
__global__ __launch_bounds__(256) void qk_pe_mfma(
    const float* __restrict__ src, const ushort* __restrict__ Wbf,
    const float* __restrict__ bias, ushort* __restrict__ out)
{
    __shared__ __align__(16) ushort xT[160 * 136];
    __shared__ __align__(16) ushort exch[192 * 24];
    const int n = blockIdx.y, tvb = blockIdx.x * 160;
    const float* sn = src + (size_t)n * 204800;
    for (int i = threadIdx.x; i < 2560; i += 256) {
        int tv4 = (i & 7) + (i >> 9) * 8;
        int cp  = (i >> 3) & 63;
        float4 a = *(const float4*)(sn + (2 * cp) * 1600 + tvb + tv4 * 4);
        float4 b = *(const float4*)(sn + (2 * cp + 1) * 1600 + tvb + tv4 * 4);
        float dv = __expf(-0.14391156831212787f * (float)cp);
        float av[4] = { a.x, a.y, a.z, a.w };
        float bv[4] = { b.x, b.y, b.z, b.w };
#pragma unroll
        for (int e = 0; e < 4; e++) {
            int tv = tvb + tv4 * 4 + e;
            int tt = tv / 25;
            float pos = (float)(tv - tt * 25);   // spatial PE
            float ang = pos * dv;
            uint p = (uint)f2bf(av[e] + __sinf(ang)) | ((uint)f2bf(bv[e] + __cosf(ang)) << 16);
            ((uint*)xT)[(tv4 * 4 + e) * 68 + cp] = p;
        }
    }
    __syncthreads();
    const int lane = threadIdx.x & 63, wave = threadIdx.x >> 6;
    const int l15 = lane & 15, kg = lane >> 4;
    const int rb = wave * 48;
    short8v wf[3][4];
#pragma unroll
    for (int nt = 0; nt < 3; nt++)
#pragma unroll
        for (int k = 0; k < 4; k++)
            wf[nt][k] = *(const short8v*)&Wbf[(rb + nt * 16 + l15) * 128 + k * 32 + kg * 8];
    float bsv[3];
#pragma unroll
    for (int nt = 0; nt < 3; nt++) bsv[nt] = bias[rb + nt * 16 + l15];
    ushort* on = out + (size_t)n * 307200;
    for (int mt = 0; mt < 10; mt++) {
        short8v af[4];
#pragma unroll
        for (int k = 0; k < 4; k++)
            af[k] = *(short8v*)&xT[(mt * 16 + l15) * 136 + k * 32 + kg * 8];
        f32x4 accs[3];
#pragma unroll
        for (int nt = 0; nt < 3; nt++) {
            f32x4 acc = {0.f, 0.f, 0.f, 0.f};
#pragma unroll
            for (int k = 0; k < 4; k++)
                acc = __builtin_amdgcn_mfma_f32_16x16x32_bf16(af[k], wf[nt][k], acc, 0, 0, 0);
            accs[nt] = acc;
        }
        __syncthreads();
#pragma unroll
        for (int nt = 0; nt < 3; nt++) {
            uint2 pk;
            pk.x = (uint)f2bf(accs[nt][0] + bsv[nt]) | ((uint)f2bf(accs[nt][1] + bsv[nt]) << 16);
            pk.y = (uint)f2bf(accs[nt][2] + bsv[nt]) | ((uint)f2bf(accs[nt][3] + bsv[nt]) << 16);
            *(uint2*)&exch[(rb + nt * 16 + l15) * 24 + kg * 4] = pk;
        }
        __syncthreads();
        for (int i = threadIdx.x; i < 384; i += 256) {
            int r = i >> 1, hh = i & 1;
            *(uint4*)(on + (size_t)r * 1600 + tvb + mt * 16 + hh * 8) =
                *(const uint4*)&exch[r * 24 + hh * 8];
        }
    }
}

// -------- qk_pe_bf (MFMA, bf16 y src + temporal PE): qk[n][192r][1600tv] --------
__global__ __launch_bounds__(256) void qk_pe_bf(
    const ushort* __restrict__ ybf, const ushort* __restrict__ Wbf,
    const float* __restrict__ bias, ushort* __restrict__ out)
{
    __shared__ __align__(16) ushort xT[160 * 136];
    __shared__ __align__(16) ushort exch[192 * 24];
    const int n = blockIdx.y, tvb = blockIdx.x * 160;
    const ushort* yq = ybf + (size_t)n * 204800;
    for (int i = threadIdx.x; i < 10240; i += 256) {
        int tv = i >> 6, cp = i & 63;
        uint w = *(const uint*)(yq + (size_t)(tvb + tv) * 128 + cp * 2);
        int t = (tvb + tv) / 25;
        float dv = __expf(-0.14391156831212787f * (float)cp);
        float ang = (float)t * dv;
        float lo = bf2f((ushort)(w & 0xffffu)) + __sinf(ang);
        float hi = bf2f((ushort)(w >> 16)) + __cosf(ang);
        ((uint*)xT)[tv * 68 + cp] = (uint)f2bf(lo) | ((uint)f2bf(hi) << 16);
    }
    __syncthreads();
    const int lane = threadIdx.x & 63, wave = threadIdx.x >> 6;
    const int l15 = lane & 15, kg = lane >> 4;
    const int rb = wave * 48;
    short8v wf[3][4];
#pragma unroll
    for (int nt = 0; nt < 3; nt++)
#pragma unroll
        for (int k = 0; k < 4; k++)
            wf[nt][k] = *(const short8v*)&Wbf[(rb + nt * 16 + l15) * 128 + k * 32 + kg * 8];
    float bsv[3];
#pragma unroll
    for (int nt = 0; nt < 3; nt++) bsv[nt] = bias[rb + nt * 16 + l15];
    ushort* on = out + (size_t)n * 307200;
    for (int mt = 0; mt < 10; mt++) {
        short8v af[4];
#pragma unroll
        for (int k = 0; k < 4; k++)
            af[k] = *(short8v*)&xT[(mt * 16 + l15) * 136 + k * 32 + kg * 8];
        f32x4 accs[3];
#pragma unroll
        for (int nt = 0; nt < 3; nt++) {
            f32x4 acc = {0.f, 0.f, 0.f, 0.f};
#pragma unroll
            for (int k = 0; k < 4; k++)
                acc = __builtin_amdgcn_mfma_f32_16x16x32_bf16(af[k], wf[nt][k], acc, 0, 0, 0);
            accs[nt] = acc;
        }
        __syncthreads();
#pragma unroll
        for (int nt = 0; nt < 3; nt++) {
            uint2 pk;
            pk.x = (uint)f2bf(accs[nt][0] + bsv[nt]) | ((uint)f2bf(accs[nt][1] + bsv[nt]) << 16);
            pk.y = (uint)f2bf(accs[nt][2] + bsv[nt]) | ((uint)f2bf(accs[nt][3] + bsv[nt]) << 16);
            *(uint2*)&exch[(rb + nt * 16 + l15) * 24 + kg * 4] = pk;
        }
        __syncthreads();
        for (int i = threadIdx.x; i < 384; i += 256) {
            int r = i >> 1, hh = i & 1;
            *(uint4*)(on + (size_t)r * 1600 + tvb + mt * 16 + hh * 8) =
                *(const uint4*)&exch[r * 24 + hh * 8];
        }
    }
}

// -------- att_s (MFMA) -> attS_bf[n][32v][96k] bf16, k=s*32+u, pads zeroed --------
__global__ __launch_bounds__(256) void att_s_mfma(
    const ushort* __restrict__ qk, const float* __restrict__ alphas,
    const float* __restrict__ att0, ushort* __restrict__ attS_bf)
{
    __shared__ __align__(16) ushort Qs[32 * 520];
    __shared__ __align__(16) ushort Ks[32 * 520];
    const int s = blockIdx.x, n = blockIdx.y;
    const ushort* qb = qk + (size_t)n * 307200 + (size_t)(s * 32) * 1600;
    const ushort* kb = qb + 96 * 1600;
    for (int i = threadIdx.x; i < 3072; i += 256) {
        int v = i / 96, k = i - v * 96;
        if (v >= 25 || (k & 31) >= 25) attS_bf[(size_t)n * 3072 + i] = 0;
    }
    const int lane = threadIdx.x & 63, wave = threadIdx.x >> 6;
    const int l15 = lane & 15, kg = lane >> 4;
    const int mt = wave >> 1, nt = wave & 1;
    f32x4 acc = {0.f, 0.f, 0.f, 0.f};
    for (int rc = 0; rc < 4; rc++) {
        __syncthreads();
        for (int i = threadIdx.x; i < 6400; i += 256) {
            int rl = i / 800, j = i - rl * 800;
            uint uq = *(const uint*)(qb + (rc * 8 + rl) * 1600 + j * 2);
            uint uk = *(const uint*)(kb + (rc * 8 + rl) * 1600 + j * 2);
            int tv = j * 2;
            int t0 = tv / 25, u0 = tv - t0 * 25;
            int t1 = (tv + 1) / 25, u1 = (tv + 1) - t1 * 25;
            Qs[u0 * 520 + rl * 64 + t0] = (ushort)(uq & 0xffffu);
            Qs[u1 * 520 + rl * 64 + t1] = (ushort)(uq >> 16);
            Ks[u0 * 520 + rl * 64 + t0] = (ushort)(uk & 0xffffu);
            Ks[u1 * 520 + rl * 64 + t1] = (ushort)(uk >> 16);
        }
        __syncthreads();
#pragma unroll
        for (int ks = 0; ks < 16; ks++) {
            short8v a = *(const short8v*)&Qs[(mt * 16 + l15) * 520 + ks * 32 + kg * 8];
            short8v b = *(const short8v*)&Ks[(nt * 16 + l15) * 520 + ks * 32 + kg * 8];
            acc = __builtin_amdgcn_mfma_f32_16x16x32_bf16(a, b, acc, 0, 0, 0);
        }
    }
    float alpha = alphas[s];
#pragma unroll
    for (int rr = 0; rr < 4; rr++) {
        int u = mt * 16 + kg * 4 + rr, v = nt * 16 + l15;
        if (u < 25 && v < 25)
            attS_bf[(size_t)n * 3072 + v * 96 + s * 32 + u] =
                f2bf(tanhf(acc[rr] * (1.0f / 2048.0f)) * alpha + att0[s * 625 + u * 25 + v]);
    }
}

// -------- att_t (MFMA) -> attT_bf[n][64q][192k] bf16, k=s*64+t --------
__global__ __launch_bounds__(256) void att_t_mfma(
    const ushort* __restrict__ qk, const float* __restrict__ alphat,
    const float* __restrict__ att0, ushort* __restrict__ attT_bf)
{
    __shared__ __align__(16) ushort Qt[8 * 64 * 40];
    __shared__ __align__(16) ushort Kt[8 * 64 * 40];
    const int s = blockIdx.x, n = blockIdx.y;
    const ushort* qb = qk + (size_t)n * 307200 + (size_t)(s * 32) * 1600;
    const ushort* kb = qb + 96 * 1600;
    for (int i = threadIdx.x; i < 10240; i += 256) {
        ((uint*)Qt)[i] = 0u;
        ((uint*)Kt)[i] = 0u;
    }
    const int lane = threadIdx.x & 63, wave = threadIdx.x >> 6;
    const int l15 = lane & 15, kg = lane >> 4;
    const int mt = wave;
    f32x4 acc[4];
#pragma unroll
    for (int i = 0; i < 4; i++) acc[i] = (f32x4){0.f, 0.f, 0.f, 0.f};
    for (int rc = 0; rc < 4; rc++) {
        __syncthreads();
        for (int i = threadIdx.x; i < 6400; i += 256) {
            int rl = i / 800, j = i - rl * 800;
            uint uq = *(const uint*)(qb + (rc * 8 + rl) * 1600 + j * 2);
            uint uk = *(const uint*)(kb + (rc * 8 + rl) * 1600 + j * 2);
            int tv = j * 2;
            int t0 = tv / 25, v0 = tv - t0 * 25;
            int t1 = (tv + 1) / 25, v1 = (tv + 1) - t1 * 25;
            Qt[(rl * 64 + t0) * 40 + v0] = (ushort)(uq & 0xffffu);
            Qt[(rl * 64 + t1) * 40 + v1] = (ushort)(uq >> 16);
            Kt[(rl * 64 + t0) * 40 + v0] = (ushort)(uk & 0xffffu);
            Kt[(rl * 64 + t1) * 40 + v1] = (ushort)(uk >> 16);
        }
        __syncthreads();
#pragma unroll
        for (int rl = 0; rl < 8; rl++) {
            short8v a = *(const short8v*)&Qt[(rl * 64 + mt * 16 + l15) * 40 + kg * 8];
#pragma unroll
            for (int nq = 0; nq < 4; nq++) {
                short8v b = *(const short8v*)&Kt[(rl * 64 + nq * 16 + l15) * 40 + kg * 8];
                acc[nq] = __builtin_amdgcn_mfma_f32_16x16x32_bf16(a, b, acc[nq], 0, 0, 0);
            }
        }
    }
    float alpha = alphat[s];
#pragma unroll
    for (int nq = 0; nq < 4; nq++) {
        int q = nq * 16 + l15;
        ushort w4[4];
#pragma unroll
        for (int rr = 0; rr < 4; rr++) {
            int t = mt * 16 + kg * 4 + rr;
            w4[rr] = f2bf(tanhf(acc[nq][rr] * (1.0f / 800.0f)) * alpha +
                          att0[s * 4096 + t * 64 + q]);
        }
        uint2 pk;
        pk.x = (uint)w4[0] | ((uint)w4[1] << 16);
        pk.y = (uint)w4[2] | ((uint)w4[3] << 16);
        *(uint2*)(attT_bf + (size_t)n * 12288 + q * 192 + s * 64 + mt * 16 + kg * 4) = pk;
    }
}

// ------- s_fused: spatial post-attention, one block per (n, 2t); emits y_bf[tv][128c] -------
__global__ __launch_bounds__(256) void s_fused(
    const float* __restrict__ x, const ushort* __restrict__ Wo /*[3][128o][128c]*/,
    const ushort* __restrict__ attS /*[n][32v][96k]*/, const ushort* __restrict__ Wf,
    const float* __restrict__ bnO, const float* __restrict__ boO,
    const float* __restrict__ bnF, const float* __restrict__ bfF,
    ushort* __restrict__ ybf)
{
    __shared__ __align__(16) ushort xT[64 * 136];
    __shared__ __align__(16) ushort uni[64 * 136];
    __shared__ float sc1[128], of1[128], sc2[128], of2[128];
    const int n = blockIdx.y, tb = blockIdx.x;
    const int tvg0 = tb * 50;
    if (threadIdx.x < 128) {
        int o = threadIdx.x;
        float s1 = bnO[o] * rsqrtf(bnO[384 + o] + 1e-5f);
        sc1[o] = s1; of1[o] = (boO[o] - bnO[256 + o]) * s1 + bnO[128 + o];
    } else {
        int o = threadIdx.x - 128;
        float s2 = bnF[o] * rsqrtf(bnF[384 + o] + 1e-5f);
        sc2[o] = s2; of2[o] = (bfF[o] - bnF[256 + o]) * s2 + bnF[128 + o];
    }
    ushort* Bt = uni;
    for (int i = threadIdx.x; i < 1792; i += 256) {
        int nr = i / 7, k = 25 + i % 7;
        Bt[nr * 32 + (((k >> 3) ^ ((nr >> 1) & 3)) << 3) + (k & 7)] = 0;
    }
    const float* xn = x + (size_t)n * 204800;
    for (int i = threadIdx.x; i < 3200; i += 256) {
        int c = i / 25, j2 = i - c * 25;
        float2 v2 = *(const float2*)(xn + c * 1600 + tvg0 + j2 * 2);
        xT[(j2 * 2) * 136 + c]     = f2bf(v2.x);
        xT[(j2 * 2 + 1) * 136 + c] = f2bf(v2.y);
    }
    __syncthreads();
    const int lane = threadIdx.x & 63, wave = threadIdx.x >> 6;
    const int l15 = lane & 15, kg = lane >> 4;
    const int ob = wave * 32, jb = wave * 4;
    f32x4 accS[2][4];
#pragma unroll
    for (int mt = 0; mt < 2; mt++)
#pragma unroll
        for (int jj = 0; jj < 4; jj++) accS[mt][jj] = (f32x4){0.f, 0.f, 0.f, 0.f};
    const ushort* An = attS + (size_t)n * 3072;
    for (int s = 0; s < 3; s++) {
        short8v bW[2][4];
#pragma unroll
        for (int ot = 0; ot < 2; ot++)
#pragma unroll
            for (int k = 0; k < 4; k++)
                bW[ot][k] = *(const short8v*)&Wo[s * 16384 +
                             (ob + ot * 16 + l15) * 128 + k * 32 + kg * 8];
#pragma unroll
        for (int tt = 0; tt < 4; tt++) {
            short8v aX[4];
#pragma unroll
            for (int k = 0; k < 4; k++)
                aX[k] = *(short8v*)&xT[(tt * 16 + l15) * 136 + k * 32 + kg * 8];
            f32x4 h0 = {0.f, 0.f, 0.f, 0.f}, h1 = {0.f, 0.f, 0.f, 0.f};
#pragma unroll
            for (int k = 0; k < 4; k++) {
                h0 = __builtin_amdgcn_mfma_f32_16x16x32_bf16(aX[k], bW[0][k], h0, 0, 0, 0);
                h1 = __builtin_amdgcn_mfma_f32_16x16x32_bf16(aX[k], bW[1][k], h1, 0, 0, 0);
            }
#pragma unroll
            for (int rr = 0; rr < 4; rr++) {
                int tv = tt * 16 + kg * 4 + rr;
                if (tv < 50) {
                    int tl = tv >= 25 ? 1 : 0, u = tv - tl * 25;
                    int n0 = tl * 128 + ob + l15;
                    int n1 = n0 + 16;
                    Bt[n0 * 32 + (((u >> 3) ^ ((n0 >> 1) & 3)) << 3) + (u & 7)] = f2bf(h0[rr]);
                    Bt[n1 * 32 + (((u >> 3) ^ ((n1 >> 1) & 3)) << 3) + (u & 7)] = f2bf(h1[rr]);
                }
            }
        }
        __syncthreads();
        short8v aA[2];
#pragma unroll
        for (int mt = 0; mt < 2; mt++)
            aA[mt] = *(const short8v*)(An + (mt * 16 + l15) * 96 + s * 32 + kg * 8);
#pragma unroll
        for (int jj = 0; jj < 4; jj++) {
            int nr = (jb + jj) * 16 + l15;
            short8v b = *(const short8v*)&Bt[nr * 32 + ((kg ^ ((nr >> 1) & 3)) << 3)];
#pragma unroll
            for (int mt = 0; mt < 2; mt++)
                accS[mt][jj] = __builtin_amdgcn_mfma_f32_16x16x32_bf16(aA[mt], b, accS[mt][jj], 0, 0, 0);
        }
        __syncthreads();
    }
#pragma unroll
    for (int mt = 0; mt < 2; mt++)
#pragma unroll
        for (int jj = 0; jj < 4; jj++) {
            int nr = (jb + jj) * 16 + l15;
            int tl = nr >> 7, o = nr & 127;
            float sc = sc1[o], of = of1[o];
#pragma unroll
            for (int rr = 0; rr < 4; rr++) {
                int v = mt * 16 + kg * 4 + rr;
                if (v < 25) {
                    int tvl = tl * 25 + v;
                    float h = accS[mt][jj][rr] * sc + of + bf2f(xT[tvl * 136 + o]);
                    h = h > 0.f ? h : 0.1f * h;
                    uni[tvl * 136 + o] = f2bf(h);
                }
            }
        }
    __syncthreads();
    short8v aF[2][4];
#pragma unroll
    for (int mt = 0; mt < 2; mt++)
#pragma unroll
        for (int k = 0; k < 4; k++)
            aF[mt][k] = *(const short8v*)&Wf[(ob + mt * 16 + l15) * 128 + k * 32 + kg * 8];
    f32x4 c0s[4], c1s[4];
#pragma unroll
    for (int nt = 0; nt < 4; nt++) {
        short8v bY[4];
#pragma unroll
        for (int k = 0; k < 4; k++)
            bY[k] = *(short8v*)&uni[(nt * 16 + l15) * 136 + k * 32 + kg * 8];
        f32x4 c0 = {0.f, 0.f, 0.f, 0.f}, c1 = {0.f, 0.f, 0.f, 0.f};
#pragma unroll
        for (int k = 0; k < 4; k++) {
            c0 = __builtin_amdgcn_mfma_f32_16x16x32_bf16(aF[0][k], bY[k], c0, 0, 0, 0);
            c1 = __builtin_amdgcn_mfma_f32_16x16x32_bf16(aF[1][k], bY[k], c1, 0, 0, 0);
        }
        c0s[nt] = c0; c1s[nt] = c1;
    }
    __syncthreads();
#pragma unroll
    for (int nt = 0; nt < 4; nt++) {
        int tv = nt * 16 + l15;
#pragma unroll
        for (int rr = 0; rr < 4; rr++) {
            {
                int o = ob + kg * 4 + rr;
                float h = c0s[nt][rr] * sc2[o] + of2[o] + bf2f(xT[tv * 136 + o]);
                uni[tv * 136 + o] = f2bf(h > 0.f ? h : 0.1f * h);
            }
            {
                int o = ob + 16 + kg * 4 + rr;
                float h = c1s[nt][rr] * sc2[o] + of2[o] + bf2f(xT[tv * 136 + o]);
                uni[tv * 136 + o] = f2bf(h > 0.f ? h : 0.1f * h);
            }
        }
    }
    __syncthreads();
    uint* dst = (uint*)(ybf + (size_t)n * 204800 + (size_t)tvg0 * 128);
    for (int i = threadIdx.x; i < 3200; i += 256) {
        int tv = i >> 6, cp = i & 63;
        dst[tv * 64 + cp] = ((const uint*)uni)[tv * 68 + cp];
    }
}

// ------- t_fused: temporal t1+t2+res+Wf-conv+res per (n, v); writes z bf16 IN PLACE over ybf -------
__global__ __launch_bounds__(256) void t_fused(
    ushort* __restrict__ ybuf /* y in, z out (same rows) */,
    const ushort* __restrict__ Wo /*[3][128o][128c]*/,
    const ushort* __restrict__ Wf /*[128o][128c]*/,
    const ushort* __restrict__ attT /*[n][64q][192]*/,
    const float* __restrict__ bn1, const float* __restrict__ bo1,
    const float* __restrict__ bn2, const float* __restrict__ bf2v)
{
    __shared__ __align__(16) ushort yS[64 * 136];   // [t][c] residual + t1 input
    __shared__ __align__(16) ushort uni[128 * 72];  // Gl[o][72] -> y1[q][136] -> z exch[q][136]
    __shared__ float sc1[128], of1[128], sc2[128], of2[128];
    const int v = blockIdx.x, np = blockIdx.y;
    if (threadIdx.x < 128) {
        int o = threadIdx.x;
        float sc = bn1[o] * rsqrtf(bn1[384 + o] + 1e-5f);
        sc1[o] = sc;
        of1[o] = (bo1[o] - bn1[256 + o]) * sc + bn1[128 + o];
    } else {
        int o = threadIdx.x - 128;
        float sc = bn2[o] * rsqrtf(bn2[384 + o] + 1e-5f);
        sc2[o] = sc;
        of2[o] = (bf2v[o] - bn2[256 + o]) * sc + bn2[128 + o];
    }
    ushort* yq = ybuf + (size_t)np * 204800;
    for (int i = threadIdx.x; i < 4096; i += 256) {
        int t = i >> 6, cp = i & 63;
        ((uint*)yS)[t * 68 + cp] = *(const uint*)(yq + (size_t)(t * 25 + v) * 128 + cp * 2);
    }
    __syncthreads();
    const int lane = threadIdx.x & 63, wave = threadIdx.x >> 6;
    const int l15 = lane & 15, kg = lane >> 4;
    const int ob = wave * 32;
    const ushort* An = attT + (size_t)np * 12288;
    ushort* Gl = uni;
    f32x4 acc[4][2];
#pragma unroll
    for (int mt = 0; mt < 4; mt++)
#pragma unroll
        for (int jj = 0; jj < 2; jj++) acc[mt][jj] = (f32x4){0.f, 0.f, 0.f, 0.f};
    for (int s = 0; s < 3; s++) {
        short8v bW[2][4];
#pragma unroll
        for (int nt = 0; nt < 2; nt++)
#pragma unroll
            for (int k = 0; k < 4; k++)
                bW[nt][k] = *(const short8v*)&Wo[s * 16384 +
                             (ob + nt * 16 + l15) * 128 + k * 32 + kg * 8];
#pragma unroll
        for (int mt = 0; mt < 4; mt++) {
            short8v aX[4];
#pragma unroll
            for (int k = 0; k < 4; k++)
                aX[k] = *(short8v*)&yS[(mt * 16 + l15) * 136 + k * 32 + kg * 8];
            f32x4 g0 = {0.f, 0.f, 0.f, 0.f}, g1 = {0.f, 0.f, 0.f, 0.f};
#pragma unroll
            for (int k = 0; k < 4; k++) {
                g0 = __builtin_amdgcn_mfma_f32_16x16x32_bf16(aX[k], bW[0][k], g0, 0, 0, 0);
                g1 = __builtin_amdgcn_mfma_f32_16x16x32_bf16(aX[k], bW[1][k], g1, 0, 0, 0);
            }
#pragma unroll
            for (int rr = 0; rr < 4; rr++) {
                int t = mt * 16 + kg * 4 + rr;
                Gl[(ob + l15) * 72 + t]      = f2bf(g0[rr]);
                Gl[(ob + 16 + l15) * 72 + t] = f2bf(g1[rr]);
            }
        }
        __syncthreads();
#pragma unroll
        for (int ks = 0; ks < 2; ks++) {
            short8v b2[2];
#pragma unroll
            for (int jj = 0; jj < 2; jj++)
                b2[jj] = *(short8v*)&Gl[(ob + jj * 16 + l15) * 72 + ks * 32 + kg * 8];
#pragma unroll
            for (int mt = 0; mt < 4; mt++) {
                short8v a2 = *(const short8v*)(An + (mt * 16 + l15) * 192 + s * 64 + ks * 32 + kg * 8);
#pragma unroll
                for (int jj = 0; jj < 2; jj++)
                    acc[mt][jj] = __builtin_amdgcn_mfma_f32_16x16x32_bf16(a2, b2[jj], acc[mt][jj], 0, 0, 0);
            }
        }
        __syncthreads();
    }
    // phase 2: y1[q][c] = lrelu(y + BN1(acc)) into uni
#pragma unroll
    for (int mt = 0; mt < 4; mt++)
#pragma unroll
        for (int jj = 0; jj < 2; jj++) {
            int o = ob + jj * 16 + l15;
            float sc = sc1[o], of = of1[o];
#pragma unroll
            for (int rr = 0; rr < 4; rr++) {
                int q = mt * 16 + kg * 4 + rr;
                float h = acc[mt][jj][rr] * sc + of + bf2f(yS[q * 136 + o]);
                h = h > 0.f ? h : 0.1f * h;
                uni[q * 136 + o] = f2bf(h);
            }
        }
    __syncthreads();
    // phase 3: z = lrelu(y + BN2(Wf @ y1)); all MFMAs first, then exchange via uni, then drain
    short8v aF[2][4];
#pragma unroll
    for (int ot = 0; ot < 2; ot++)
#pragma unroll
        for (int k = 0; k < 4; k++)
            aF[ot][k] = *(const short8v*)&Wf[(ob + ot * 16 + l15) * 128 + k * 32 + kg * 8];
    f32x4 c0s[4], c1s[4];
#pragma unroll
    for (int qt = 0; qt < 4; qt++) {
        short8v bY[4];
#pragma unroll
        for (int k = 0; k < 4; k++)
            bY[k] = *(short8v*)&uni[(qt * 16 + l15) * 136 + k * 32 + kg * 8];
        f32x4 c0 = {0.f, 0.f, 0.f, 0.f}, c1 = {0.f, 0.f, 0.f, 0.f};
#pragma unroll
        for (int k = 0; k < 4; k++) {
            c0 = __builtin_amdgcn_mfma_f32_16x16x32_bf16(aF[0][k], bY[k], c0, 0, 0, 0);
            c1 = __builtin_amdgcn_mfma_f32_16x16x32_bf16(aF[1][k], bY[k], c1, 0, 0, 0);
        }
        c0s[qt] = c0; c1s[qt] = c1;
    }
    __syncthreads();
#pragma unroll
    for (int qt = 0; qt < 4; qt++) {
        int q = qt * 16 + l15;
#pragma unroll
        for (int rr = 0; rr < 4; rr++) {
            {
                int o = ob + kg * 4 + rr;
                float h = c0s[qt][rr] * sc2[o] + of2[o] + bf2f(yS[q * 136 + o]);
                uni[q * 136 + o] = f2bf(h > 0.f ? h : 0.1f * h);
            }
            {
                int o = ob + 16 + kg * 4 + rr;
                float h = c1s[qt][rr] * sc2[o] + of2[o] + bf2f(yS[q * 136 + o]);
                uni[q * 136 + o] = f2bf(h > 0.f ? h : 0.1f * h);
            }
        }
    }
    __syncthreads();
    // drain: 64 rows (q*25+v) x 256 B contiguous, in place over ybuf (block-disjoint rows)
    for (int i = threadIdx.x; i < 4096; i += 256) {
        int q = i >> 6, cp = i & 63;
        *(uint*)(yq + (size_t)(q * 25 + v) * 128 + cp * 2) = ((const uint*)uni)[q * 68 + cp];
    }
}

// ------- z_out: out fp32 [n][c][tv] = transpose of z bf16 [n][tv][128c] -------
__global__ __launch_bounds__(256) void z_out(
    const ushort* __restrict__ zbf, float* __restrict__ outp)
{
    __shared__ __align__(16) ushort xT[160 * 140];  // stride 140 (70 uints) to spread banks
    const int np = blockIdx.y, tvb = blockIdx.x * 160;
    const ushort* pp = zbf + (size_t)np * 204800 + (size_t)tvb * 128;
    for (int i = threadIdx.x; i < 10240; i += 256) {
        int tv = i >> 6, cp = i & 63;
        ((uint*)xT)[tv * 70 + cp] = *(const uint*)(pp + tv * 128 + cp * 2);
    }
    __syncthreads();
    float* on = outp + (size_t)np * 204800;
    for (int i = threadIdx.x; i < 5120; i += 256) {
        int c = i / 40, w4 = i - c * 40;
        float4 o4;
        o4.x = bf2f(xT[(w4 * 4 + 0) * 140 + c]);
        o4.y = bf2f(xT[(w4 * 4 + 1) * 140 + c]);
        o4.z = bf2f(xT[(w4 * 4 + 2) * 140 + c]);
        o4.w = bf2f(xT[(w4 * 4 + 3) * 140 + c]);
        *(float4*)(on + (size_t)c * 1600 + tvb + w4 * 4) = o4;
    }
}

extern "C" void kernel_launch(void* const* d_in, const int* in_sizes, int n_in,
                              void* d_out, int out_size, void* d_ws, size_t ws_size,
                              hipStream_t stream)
{
    (void)in_sizes; (void)n_in; (void)out_size; (void)ws_size;
    const float* x      = (const float*)d_in[0];
    const float* Wqk_s  = (const float*)d_in[1];
    const float* bqk_s  = (const float*)d_in[2];
    const float* alphas = (const float*)d_in[3];
    const float* att0s  = (const float*)d_in[4];
    const float* Wo_s   = (const float*)d_in[5];
    const float* bo_s   = (const float*)d_in[6];
    const float* bn_o_s = (const float*)d_in[7];
    const float* Wf_s   = (const float*)d_in[8];
    const float* bf_s   = (const float*)d_in[9];
    const float* bn_f_s = (const float*)d_in[10];
    const float* Wqk_t  = (const float*)d_in[11];
    const float* bqk_t  = (const float*)d_in[12];
    const float* alphat = (const float*)d_in[13];
    const float* att0t  = (const float*)d_in[14];
    const float* Wo_t   = (const float*)d_in[15];
    const float* bo_t   = (const float*)d_in[16];
    const float* bn_o_t = (const float*)d_in[17];
    const float* Wf_t   = (const float*)d_in[18];
    const float* bf_t   = (const float*)d_in[19];
    const float* bn_f_t = (const float*)d_in[20];

    float* out = (float*)d_out;
    ushort* qk_d    = (ushort*)d_out;                      // dead until z_out writes
    ushort* ybf     = (ushort*)d_ws;                       // y_bf, then z (in place)
    ushort* attS_bf = (ushort*)((char*)d_ws + 78643200);
    ushort* attT_bf = (ushort*)((char*)d_ws + 79603200);
    ushort* W16     = (ushort*)((char*)d_ws + 85894656);
    const ushort* WoS_bf  = W16;
    const ushort* WfS_bf  = W16 + 49152;
    const ushort* WoT_bf  = W16 + 65536;
    const ushort* WfT_bf  = W16 + 114688;
    const ushort* WqkS_bf = W16 + 131072;
    const ushort* WqkT_bf = W16 + 155648;

    wt_prep<<<704, 256, 0, stream>>>(Wo_s, Wf_s, Wo_t, Wf_t, Wqk_s, Wqk_t, W16);

    dim3 gqk(10, 128), gatt(3, 128), gsf(32, 128), gtf(25, 128), gzo(10, 128);

    // ---- spatial ----
    qk_pe_mfma<<<gqk, 256, 0, stream>>>(x, WqkS_bf, bqk_s, qk_d);
    att_s_mfma<<<gatt, 256, 0, stream>>>(qk_d, alphas, att0s, attS_bf);
    s_fused<<<gsf, 256, 0, stream>>>(x, WoS_bf, attS_bf, WfS_bf,
                                     bn_o_s, bo_s, bn_f_s, bf_s, ybf);

    // ---- temporal ----
    qk_pe_bf<<<gqk, 256, 0, stream>>>(ybf, WqkT_bf, bqk_t, qk_d);
    att_t_mfma<<<gatt, 256, 0, stream>>>(qk_d, alphat, att0t, attT_bf);
    t_fused<<<gtf, 256, 0, stream>>>(ybf, WoT_bf, WfT_bf, attT_bf,
                                     bn_o_t, bo_t, bn_f_t, bf_t);
    z_out<<<gzo, 256, 0, stream>>>(ybf, out);
}